// Round 15
// baseline (149.891 us; speedup 1.0000x reference)
//
#include <hip/hip_runtime.h>
#include <hip/hip_fp16.h>
#include <cstdint>
#include <cstddef>
#include <math.h>

// Problem constants (from reference)
#define NNODES 20000
#define NEDGES 320000
#define TDIM   8
#define CDIM   32
#define RROWS  (NNODES * TDIM)           // 160000 rows of 32 values (= 2500*64)
#define NELEM  (RROWS * CDIM)            // 5,120,000 elements
#define NODEB  79                        // ceil(NNODES/256)

static __device__ __forceinline__ unsigned pk2(float a, float b) {
    __half2 h = __floats2half2_rn(a, b);
    return *reinterpret_cast<unsigned*>(&h);
}

// convert 8 packed halves (uint4) to 8 floats
static __device__ __forceinline__ void cvt8(uint4 r, float* a) {
    float2 f;
    f = __half22float2(*reinterpret_cast<__half2*>(&r.x)); a[0] = f.x; a[1] = f.y;
    f = __half22float2(*reinterpret_cast<__half2*>(&r.y)); a[2] = f.x; a[3] = f.y;
    f = __half22float2(*reinterpret_cast<__half2*>(&r.z)); a[4] = f.x; a[5] = f.y;
    f = __half22float2(*reinterpret_cast<__half2*>(&r.w)); a[6] = f.x; a[7] = f.y;
}

// ---------------------------------------------------------------------------
// Shared agg edge loop: 4 edges in flight PER HALF-WAVE (8/wave), next-4
// index prefetch under gather latency.  R13 post-mortem: aggfuse ran at
// exactly hbm_bytes/2TB/s -> latency/MLP-bound on the random 512B gathers;
// doubling in-flight gathers is the lever (VGPR ~64, occupancy unaffected).
// ---------------------------------------------------------------------------
static __device__ __forceinline__ void agg_edges(
    const int* __restrict__ csr_src, const char* __restrict__ hub,
    uint32_t rowOff, const float b[8], int k0, int k1, int half, float m[8])
{
    int k = k0;
    int e0 = 0, e1 = 0, e2 = 0, e3 = 0;
    if (k + 8 <= k1) {
        const int* p = csr_src + k + half * 4;
        e0 = p[0]; e1 = p[1]; e2 = p[2]; e3 = p[3];
    }
    while (k + 8 <= k1) {
        uint4 r0 = *(const uint4*)(hub + (((uint32_t)e0 << 9) + rowOff));
        uint4 r1 = *(const uint4*)(hub + (((uint32_t)e1 << 9) + rowOff));
        uint4 r2 = *(const uint4*)(hub + (((uint32_t)e2 << 9) + rowOff));
        uint4 r3 = *(const uint4*)(hub + (((uint32_t)e3 << 9) + rowOff));
        k += 8;
        if (k + 8 <= k1) {                   // prefetch next 4 indices
            const int* p = csr_src + k + half * 4;
            e0 = p[0]; e1 = p[1]; e2 = p[2]; e3 = p[3];
        }
        float a0[8], a1[8], a2[8], a3[8];
        cvt8(r0, a0); cvt8(r1, a1); cvt8(r2, a2); cvt8(r3, a3);
        float q0 = 0.f, q1 = 0.f, q2 = 0.f, q3 = 0.f;
#pragma unroll
        for (int j = 0; j < 8; ++j) {
            q0 = fmaf(a0[j], b[j], q0); q1 = fmaf(a1[j], b[j], q1);
            q2 = fmaf(a2[j], b[j], q2); q3 = fmaf(a3[j], b[j], q3);
        }
        q0 += __shfl_xor(q0, 1); q1 += __shfl_xor(q1, 1);
        q2 += __shfl_xor(q2, 1); q3 += __shfl_xor(q3, 1);
        q0 += __shfl_xor(q0, 2); q1 += __shfl_xor(q1, 2);
        q2 += __shfl_xor(q2, 2); q3 += __shfl_xor(q3, 2);
        float g0 = 1.f / (1.f + __expf(-q0));
        float g1 = 1.f / (1.f + __expf(-q1));
        float g2 = 1.f / (1.f + __expf(-q2));
        float g3 = 1.f / (1.f + __expf(-q3));
#pragma unroll
        for (int j = 0; j < 8; ++j) {
            m[j] = fmaxf(m[j], fmaxf(fmaxf(a0[j] * g0, a1[j] * g1),
                                     fmaxf(a2[j] * g2, a3[j] * g3)));
        }
    }
    // tail (<8 edges): both halves process the same edge (idempotent max)
    for (; k < k1; ++k) {
        int s = csr_src[k];
        float a0[8];
        cvt8(*(const uint4*)(hub + (((uint32_t)s << 9) + rowOff)), a0);
        float q0 = 0.f;
#pragma unroll
        for (int j = 0; j < 8; ++j) q0 = fmaf(a0[j], b[j], q0);
        q0 += __shfl_xor(q0, 1);
        q0 += __shfl_xor(q0, 2);
        float g0 = 1.f / (1.f + __expf(-q0));
#pragma unroll
        for (int j = 0; j < 8; ++j) m[j] = fmaxf(m[j], a0[j] * g0);
    }
}

// ---------------------------------------------------------------------------
// init: zero counts (blocks 0..78) + WU = W@U for both layers (blocks 79..86).
// ---------------------------------------------------------------------------
__global__ __launch_bounds__(256) void init_kernel(
    const float* __restrict__ Wn1, const float* __restrict__ u1, float* __restrict__ WU1,
    const float* __restrict__ Wn2, const float* __restrict__ u2, float* __restrict__ WU2,
    int* __restrict__ counts)
{
    int blk = blockIdx.x, tid = threadIdx.x;
    if (blk < NODEB) {
        int i = blk * 256 + tid;
        if (i < NNODES) counts[i] = 0;
        return;
    }
    int b = blk - NODEB;                 // 0..7
    const float* W  = (b < 4) ? Wn1 : Wn2;
    const float* U  = (b < 4) ? u1  : u2;
    float*       WU = (b < 4) ? WU1 : WU2;
    int idx = (b & 3) * 256 + tid;       // 0..1023
    int k = idx >> 5, c = idx & 31;
    float acc = 0.f;
#pragma unroll
    for (int j = 0; j < CDIM; ++j) acc = fmaf(W[k * CDIM + j], U[j * CDIM + c], acc);
    WU[idx] = acc;
}

__global__ __launch_bounds__(256) void hist_kernel(
    const int* __restrict__ ei, int* __restrict__ counts)
{
    int e = blockIdx.x * 256 + threadIdx.x;
    if (e < NEDGES) atomicAdd(&counts[ei[NEDGES + e]], 1);
}

// ---------------------------------------------------------------------------
// Single-dispatch scan: each block redundantly sums counts before its range
// (coalesced) then local-scans its 256 counts.
// ---------------------------------------------------------------------------
__global__ __launch_bounds__(256) void scan_kernel(
    const int* __restrict__ counts,
    int* __restrict__ offsets, int* __restrict__ cursor)
{
    __shared__ int sd[256];
    int blk = blockIdx.x, tid = threadIdx.x;

    int pre = 0;
    for (int i = tid; i < blk * 256; i += 256) pre += counts[i];
    sd[tid] = pre;
    __syncthreads();
#pragma unroll
    for (int off = 128; off > 0; off >>= 1) {
        if (tid < off) sd[tid] += sd[tid + off];
        __syncthreads();
    }
    int base = sd[0];
    __syncthreads();

    int i = blk * 256 + tid;
    int v = (i < NNODES) ? counts[i] : 0;
    sd[tid] = v;
    __syncthreads();
#pragma unroll
    for (int off = 1; off < 256; off <<= 1) {
        int t = (tid >= off) ? sd[tid - off] : 0;
        __syncthreads();
        sd[tid] += t;
        __syncthreads();
    }
    int excl = base + sd[tid] - v;
    if (i < NNODES) { offsets[i] = excl; cursor[i] = excl; }
    if (i == NNODES - 1) offsets[NNODES] = NEDGES;
}

__global__ __launch_bounds__(256) void scatter_kernel(
    const int* __restrict__ ei,
    int* __restrict__ cursor,
    int* __restrict__ csr_src)
{
    int e = blockIdx.x * 256 + threadIdx.x;
    if (e < NEDGES) {
        int t = ei[NEDGES + e];
        int pos = atomicAdd(&cursor[t], 1);
        csr_src[pos] = ei[e];
    }
}

// ---------------------------------------------------------------------------
// Layer-1 linear: h16 = half(X @ W) ; hu16 = half(X @ WU).  (R9 geometry.)
// ---------------------------------------------------------------------------
__global__ __launch_bounds__(256) void linear2_kernel(
    const float* __restrict__ in,   // [RROWS, 32] f32
    const float* __restrict__ W,
    const float* __restrict__ WU,
    __half* __restrict__ h16,
    __half* __restrict__ hu16)
{
    __shared__ float sx[64][33];
    int tid = threadIdx.x;
    int rowBase = blockIdx.x * 64;

    const float4* in4 = (const float4*)(in + (size_t)rowBase * CDIM);
#pragma unroll
    for (int i = 0; i < 2; ++i) {
        int idx = tid + i * 256;
        float4 v = in4[idx];
        int r = idx >> 3, q = idx & 7;
        sx[r][4 * q + 0] = v.x; sx[r][4 * q + 1] = v.y;
        sx[r][4 * q + 2] = v.z; sx[r][4 * q + 3] = v.w;
    }
    __syncthreads();

    int lane  = tid & 63;
    int chunk = __builtin_amdgcn_readfirstlane(tid >> 6);
    int row = rowBase + lane;

    float hr[8], acc[8];
#pragma unroll
    for (int j = 0; j < 8; ++j) { hr[j] = 0.f; acc[j] = 0.f; }

    const float* Wc  = W  + chunk * 8;
    const float* WUc = WU + chunk * 8;
#pragma unroll 4
    for (int k = 0; k < CDIM; ++k) {
        float xk = sx[lane][k];
#pragma unroll
        for (int j = 0; j < 8; ++j) {
            hr[j]  = fmaf(xk, Wc[k * CDIM + j],  hr[j]);
            acc[j] = fmaf(xk, WUc[k * CDIM + j], acc[j]);
        }
    }

    uint4* hp = (uint4*)((char*)h16 + (size_t)row * 64 + chunk * 16);
    *hp = make_uint4(pk2(hr[0], hr[1]), pk2(hr[2], hr[3]),
                     pk2(hr[4], hr[5]), pk2(hr[6], hr[7]));
    uint4* up = (uint4*)((char*)hu16 + (size_t)row * 64 + chunk * 16);
    *up = make_uint4(pk2(acc[0], acc[1]), pk2(acc[2], acc[3]),
                     pk2(acc[4], acc[5]), pk2(acc[6], acc[7]));
}

// ---------------------------------------------------------------------------
// FUSED agg(layer1) + linear(layer2): 512 threads = 8 waves = 8 nodes/block.
// Phase A: 4-edge-deep agg per half-wave; c1 kept in f32 LDS.
// Phase B: wave w computes cols 4w..4w+4 of h2/hu2 for all 64 rows.
// ---------------------------------------------------------------------------
__global__ __launch_bounds__(512) void aggfuse_kernel(
    const int* __restrict__ offsets,
    const int* __restrict__ csr_src,
    const __half* __restrict__ hu16, // hu1 [RROWS,32] fp16
    const __half* __restrict__ h16,  // h1  [RROWS,32] fp16
    const float* __restrict__ W2,    // [32,32]
    const float* __restrict__ WU2,   // [32,32]
    __half* __restrict__ h2_16,      // out h2  [RROWS,32] fp16
    __half* __restrict__ hu2_16)     // out hu2 [RROWS,32] fp16
{
    __shared__ float sc1[64][33];
    int tid = threadIdx.x;
    int wid = tid >> 6;                      // 0..7, node slot
    int n = blockIdx.x * 8 + wid;
    int l64 = tid & 63;
    int half = l64 >> 5;
    int l32 = l64 & 31;
    uint32_t rowOff = (uint32_t)l32 * 16u;
    const char* hub = (const char*)hu16;

    float b[8];
    cvt8(*(const uint4*)(hub + ((uint32_t)n << 9) + rowOff), b);

    int k0 = offsets[n];
    int k1 = offsets[n + 1];

    float m[8];
#pragma unroll
    for (int j = 0; j < 8; ++j) m[j] = -INFINITY;

    agg_edges(csr_src, hub, rowOff, b, k0, k1, half, m);

#pragma unroll
    for (int j = 0; j < 8; ++j) m[j] = fmaxf(m[j], __shfl_xor(m[j], 32));

    if (half == 0) {
        bool has = (k1 > k0);
        float hv[8];
        cvt8(*(const uint4*)((const char*)h16 + ((uint32_t)n << 9) + rowOff), hv);
        int rloc = wid * 8 + (l32 >> 2);     // row within block (node-local tau)
        int cbase = (l32 & 3) * 8;
#pragma unroll
        for (int j = 0; j < 8; ++j) {
            float a = has ? m[j] : 0.f;
            float vv = hv[j] + a;
            sc1[rloc][cbase + j] = (vv >= 0.f) ? vv : 0.01f * vv;
        }
    }
    __syncthreads();

    // ---- phase B: h2/hu2 for the block's 64 rows ----
    int w = __builtin_amdgcn_readfirstlane(wid);   // 0..7, SGPR
    int r = l64;                                   // row 0..63
    float h2[4], a2[4];
#pragma unroll
    for (int j = 0; j < 4; ++j) { h2[j] = 0.f; a2[j] = 0.f; }

    const float* Wc = W2  + w * 4;       // uniform -> s_load
    const float* Uc = WU2 + w * 4;       // uniform -> s_load
#pragma unroll 4
    for (int kk = 0; kk < CDIM; ++kk) {
        float xk = sc1[r][kk];           // ds_read_b32, 2-way bank alias
#pragma unroll
        for (int j = 0; j < 4; ++j) {
            h2[j] = fmaf(xk, Wc[kk * CDIM + j], h2[j]);
            a2[j] = fmaf(xk, Uc[kk * CDIM + j], a2[j]);
        }
    }

    size_t rowg = (size_t)blockIdx.x * 64 + r;
    *(uint2*)((char*)h2_16  + rowg * 64 + w * 8) = make_uint2(pk2(h2[0], h2[1]), pk2(h2[2], h2[3]));
    *(uint2*)((char*)hu2_16 + rowg * 64 + w * 8) = make_uint2(pk2(a2[0], a2[1]), pk2(a2[2], a2[3]));
}

// ---------------------------------------------------------------------------
// Final aggregation (layer 2): 4-edge-deep agg, writes f32 d_out.
// ---------------------------------------------------------------------------
__global__ __launch_bounds__(256) void agg_kernel(
    const int* __restrict__ offsets,
    const int* __restrict__ csr_src,
    const __half* __restrict__ hu16,
    const __half* __restrict__ h16,
    float* __restrict__ outp)
{
    int tid = threadIdx.x;
    int n = blockIdx.x * 4 + (tid >> 6);
    int l64 = tid & 63;
    int half = l64 >> 5;
    int l32 = l64 & 31;
    uint32_t rowOff = (uint32_t)l32 * 16u;
    const char* hub = (const char*)hu16;

    float b[8];
    cvt8(*(const uint4*)(hub + ((uint32_t)n << 9) + rowOff), b);

    int k0 = offsets[n];
    int k1 = offsets[n + 1];

    float m[8];
#pragma unroll
    for (int j = 0; j < 8; ++j) m[j] = -INFINITY;

    agg_edges(csr_src, hub, rowOff, b, k0, k1, half, m);

#pragma unroll
    for (int j = 0; j < 8; ++j) m[j] = fmaxf(m[j], __shfl_xor(m[j], 32));

    if (half == 0) {
        bool has = (k1 > k0);
        float hv[8];
        cvt8(*(const uint4*)((const char*)h16 + ((uint32_t)n << 9) + rowOff), hv);
        float o[8];
#pragma unroll
        for (int j = 0; j < 8; ++j) {
            float a = has ? m[j] : 0.f;
            float vv = hv[j] + a;
            o[j] = (vv >= 0.f) ? vv : 0.01f * vv;
        }
        uint32_t nodeOff = (uint32_t)n * 1024u + (uint32_t)l32 * 32u;
        char* ob = (char*)outp;
        *(float4*)(ob + nodeOff)      = make_float4(o[0], o[1], o[2], o[3]);
        *(float4*)(ob + nodeOff + 16) = make_float4(o[4], o[5], o[6], o[7]);
    }
}

// ---------------------------------------------------------------------------
// Orchestration: 7 dispatches.
// ws: [counts N][offsets N+1][cursor N][WU1 1024][WU2 1024][csr E][pad]
//     [Hh1][HU1][Hh2][HU2] (fp16, 10.24MB each)
// ---------------------------------------------------------------------------
extern "C" void kernel_launch(void* const* d_in, const int* in_sizes, int n_in,
                              void* d_out, int out_size, void* d_ws, size_t ws_size,
                              hipStream_t stream)
{
    const float* X   = (const float*)d_in[0];
    const int*   ei  = (const int*)  d_in[1];
    // d_in[2]=edge_attr, d_in[4]=We1, d_in[7]=We2: dead code in reference
    const float* Wn1 = (const float*)d_in[3];
    const float* u1  = (const float*)d_in[5];
    const float* Wn2 = (const float*)d_in[6];
    const float* u2  = (const float*)d_in[8];

    int* counts  = (int*)d_ws;
    int* offsets = counts + NNODES;           // NNODES+1
    int* cursor  = offsets + NNODES + 1;
    float* WU1   = (float*)(cursor + NNODES); // 1024
    float* WU2   = WU1 + 1024;                // 1024
    int* csr     = (int*)(WU2 + 1024);        // NEDGES
    __half* Hh1  = (__half*)(((uintptr_t)(csr + NEDGES) + 255) & ~(uintptr_t)255);
    __half* HU1  = Hh1 + NELEM;
    __half* Hh2  = HU1 + NELEM;
    __half* HU2  = Hh2 + NELEM;

    const int linBlocks  = RROWS / 64;             // 2500
    const int edgeBlocks = (NEDGES + 255) / 256;   // 1250
    const int fuseBlocks = NNODES / 8;             // 2500
    const int aggBlocks  = NNODES / 4;             // 5000

    // ---- CSR + WU build ----
    init_kernel<<<NODEB + 8, 256, 0, stream>>>(Wn1, u1, WU1, Wn2, u2, WU2, counts);
    hist_kernel<<<edgeBlocks, 256, 0, stream>>>(ei, counts);
    scan_kernel<<<NODEB, 256, 0, stream>>>(counts, offsets, cursor);
    scatter_kernel<<<edgeBlocks, 256, 0, stream>>>(ei, cursor, csr);

    // ---- layer 1 linear ----
    linear2_kernel<<<linBlocks, 256, 0, stream>>>(X, Wn1, WU1, Hh1, HU1);

    // ---- fused agg1 + linear2-L2 ----
    aggfuse_kernel<<<fuseBlocks, 512, 0, stream>>>(offsets, csr, HU1, Hh1,
                                                   Wn2, WU2, Hh2, HU2);

    // ---- layer 2 agg -> output ----
    agg_kernel<<<aggBlocks, 256, 0, stream>>>(offsets, csr, HU2, Hh2, (float*)d_out);
}

// Round 16
// 138.196 us; speedup vs baseline: 1.0846x; 1.0846x over previous
//
#include <hip/hip_runtime.h>
#include <hip/hip_fp16.h>
#include <cstdint>
#include <cstddef>
#include <math.h>

// Problem constants (from reference)
#define NNODES 20000
#define NEDGES 320000
#define TDIM   8
#define CDIM   32
#define RROWS  (NNODES * TDIM)           // 160000 rows of 32 values (= 2500*64)
#define NELEM  (RROWS * CDIM)            // 5,120,000 elements
#define NODEB  79                        // ceil(NNODES/256)

static __device__ __forceinline__ unsigned pk2(float a, float b) {
    __half2 h = __floats2half2_rn(a, b);
    return *reinterpret_cast<unsigned*>(&h);
}

// convert 8 packed halves (uint4) to 8 floats
static __device__ __forceinline__ void cvt8(uint4 r, float* a) {
    float2 f;
    f = __half22float2(*reinterpret_cast<__half2*>(&r.x)); a[0] = f.x; a[1] = f.y;
    f = __half22float2(*reinterpret_cast<__half2*>(&r.y)); a[2] = f.x; a[3] = f.y;
    f = __half22float2(*reinterpret_cast<__half2*>(&r.z)); a[4] = f.x; a[5] = f.y;
    f = __half22float2(*reinterpret_cast<__half2*>(&r.w)); a[6] = f.x; a[7] = f.y;
}

// ---------------------------------------------------------------------------
// init: zero counts (blocks 0..78) + WU = W@U for both layers (blocks 79..86).
// ---------------------------------------------------------------------------
__global__ __launch_bounds__(256) void init_kernel(
    const float* __restrict__ Wn1, const float* __restrict__ u1, float* __restrict__ WU1,
    const float* __restrict__ Wn2, const float* __restrict__ u2, float* __restrict__ WU2,
    int* __restrict__ counts)
{
    int blk = blockIdx.x, tid = threadIdx.x;
    if (blk < NODEB) {
        int i = blk * 256 + tid;
        if (i < NNODES) counts[i] = 0;
        return;
    }
    int b = blk - NODEB;                 // 0..7
    const float* W  = (b < 4) ? Wn1 : Wn2;
    const float* U  = (b < 4) ? u1  : u2;
    float*       WU = (b < 4) ? WU1 : WU2;
    int idx = (b & 3) * 256 + tid;       // 0..1023
    int k = idx >> 5, c = idx & 31;
    float acc = 0.f;
#pragma unroll
    for (int j = 0; j < CDIM; ++j) acc = fmaf(W[k * CDIM + j], U[j * CDIM + c], acc);
    WU[idx] = acc;
}

__global__ __launch_bounds__(256) void hist_kernel(
    const int* __restrict__ ei, int* __restrict__ counts)
{
    int e = blockIdx.x * 256 + threadIdx.x;
    if (e < NEDGES) atomicAdd(&counts[ei[NEDGES + e]], 1);
}

// ---------------------------------------------------------------------------
// Single-dispatch scan: each block redundantly sums counts before its range
// (coalesced) then local-scans its 256 counts.
// ---------------------------------------------------------------------------
__global__ __launch_bounds__(256) void scan_kernel(
    const int* __restrict__ counts,
    int* __restrict__ offsets, int* __restrict__ cursor)
{
    __shared__ int sd[256];
    int blk = blockIdx.x, tid = threadIdx.x;

    int pre = 0;
    for (int i = tid; i < blk * 256; i += 256) pre += counts[i];
    sd[tid] = pre;
    __syncthreads();
#pragma unroll
    for (int off = 128; off > 0; off >>= 1) {
        if (tid < off) sd[tid] += sd[tid + off];
        __syncthreads();
    }
    int base = sd[0];
    __syncthreads();

    int i = blk * 256 + tid;
    int v = (i < NNODES) ? counts[i] : 0;
    sd[tid] = v;
    __syncthreads();
#pragma unroll
    for (int off = 1; off < 256; off <<= 1) {
        int t = (tid >= off) ? sd[tid - off] : 0;
        __syncthreads();
        sd[tid] += t;
        __syncthreads();
    }
    int excl = base + sd[tid] - v;
    if (i < NNODES) { offsets[i] = excl; cursor[i] = excl; }
    if (i == NNODES - 1) offsets[NNODES] = NEDGES;
}

__global__ __launch_bounds__(256) void scatter_kernel(
    const int* __restrict__ ei,
    int* __restrict__ cursor,
    int* __restrict__ csr_src)
{
    int e = blockIdx.x * 256 + threadIdx.x;
    if (e < NEDGES) {
        int t = ei[NEDGES + e];
        int pos = atomicAdd(&cursor[t], 1);
        csr_src[pos] = ei[e];
    }
}

// ---------------------------------------------------------------------------
// Layer-1 linear: h16 = half(X @ W) ; hu16 = half(X @ WU).  (R9 geometry.)
// ---------------------------------------------------------------------------
__global__ __launch_bounds__(256) void linear2_kernel(
    const float* __restrict__ in,   // [RROWS, 32] f32
    const float* __restrict__ W,
    const float* __restrict__ WU,
    __half* __restrict__ h16,
    __half* __restrict__ hu16)
{
    __shared__ float sx[64][33];
    int tid = threadIdx.x;
    int rowBase = blockIdx.x * 64;

    const float4* in4 = (const float4*)(in + (size_t)rowBase * CDIM);
#pragma unroll
    for (int i = 0; i < 2; ++i) {
        int idx = tid + i * 256;
        float4 v = in4[idx];
        int r = idx >> 3, q = idx & 7;
        sx[r][4 * q + 0] = v.x; sx[r][4 * q + 1] = v.y;
        sx[r][4 * q + 2] = v.z; sx[r][4 * q + 3] = v.w;
    }
    __syncthreads();

    int lane  = tid & 63;
    int chunk = __builtin_amdgcn_readfirstlane(tid >> 6);
    int row = rowBase + lane;

    float hr[8], acc[8];
#pragma unroll
    for (int j = 0; j < 8; ++j) { hr[j] = 0.f; acc[j] = 0.f; }

    const float* Wc  = W  + chunk * 8;
    const float* WUc = WU + chunk * 8;
#pragma unroll 4
    for (int k = 0; k < CDIM; ++k) {
        float xk = sx[lane][k];
#pragma unroll
        for (int j = 0; j < 8; ++j) {
            hr[j]  = fmaf(xk, Wc[k * CDIM + j],  hr[j]);
            acc[j] = fmaf(xk, WUc[k * CDIM + j], acc[j]);
        }
    }

    uint4* hp = (uint4*)((char*)h16 + (size_t)row * 64 + chunk * 16);
    *hp = make_uint4(pk2(hr[0], hr[1]), pk2(hr[2], hr[3]),
                     pk2(hr[4], hr[5]), pk2(hr[6], hr[7]));
    uint4* up = (uint4*)((char*)hu16 + (size_t)row * 64 + chunk * 16);
    *up = make_uint4(pk2(acc[0], acc[1]), pk2(acc[2], acc[3]),
                     pk2(acc[4], acc[5]), pk2(acc[6], acc[7]));
}

// ---------------------------------------------------------------------------
// FUSED agg(layer1) + linear(layer2): 512 threads = 8 waves = 8 nodes/block.
// Phase A (per wave = 1 node): 2-edges-per-wave agg (measured optimum: R14's
// 4-deep unroll regressed -- occupancy 58->47%, redundant tail grew).
// c1 = leaky(h1+agg1) kept in f32 LDS [64][33] (never hits HBM).
// Phase B: wave w computes cols 4w..4w+4 of h2 = c1@W2 and hu2 = c1@WU2 for
// all 64 rows; weight chunk wave-uniform -> s_load SGPR operands.
// ---------------------------------------------------------------------------
__global__ __launch_bounds__(512) void aggfuse_kernel(
    const int* __restrict__ offsets,
    const int* __restrict__ csr_src,
    const __half* __restrict__ hu16, // hu1 [RROWS,32] fp16
    const __half* __restrict__ h16,  // h1  [RROWS,32] fp16
    const float* __restrict__ W2,    // [32,32]
    const float* __restrict__ WU2,   // [32,32]
    __half* __restrict__ h2_16,      // out h2  [RROWS,32] fp16
    __half* __restrict__ hu2_16)     // out hu2 [RROWS,32] fp16
{
    __shared__ float sc1[64][33];
    int tid = threadIdx.x;
    int wid = tid >> 6;                      // 0..7, node slot
    int n = blockIdx.x * 8 + wid;
    int l64 = tid & 63;
    int half = l64 >> 5;
    int l32 = l64 & 31;
    uint32_t rowOff = (uint32_t)l32 * 16u;
    const char* hub = (const char*)hu16;

    float b[8];
    cvt8(*(const uint4*)(hub + ((uint32_t)n << 9) + rowOff), b);

    int k0 = offsets[n];
    int k1 = offsets[n + 1];

    float m[8];
#pragma unroll
    for (int j = 0; j < 8; ++j) m[j] = -INFINITY;

    int k = k0;
    int e0 = 0, e1 = 0;
    if (k + 4 <= k1) {
        e0 = csr_src[k + half];
        e1 = csr_src[k + 2 + half];
    }
    while (k + 4 <= k1) {
        uint4 r0 = *(const uint4*)(hub + (((uint32_t)e0 << 9) + rowOff));
        uint4 r1 = *(const uint4*)(hub + (((uint32_t)e1 << 9) + rowOff));
        k += 4;
        if (k + 4 <= k1) {
            e0 = csr_src[k + half];
            e1 = csr_src[k + 2 + half];
        }
        float a0[8], a1[8];
        cvt8(r0, a0); cvt8(r1, a1);
        float q0 = 0.f, q1 = 0.f;
#pragma unroll
        for (int j = 0; j < 8; ++j) { q0 = fmaf(a0[j], b[j], q0); q1 = fmaf(a1[j], b[j], q1); }
        q0 += __shfl_xor(q0, 1); q1 += __shfl_xor(q1, 1);
        q0 += __shfl_xor(q0, 2); q1 += __shfl_xor(q1, 2);
        float g0 = 1.f / (1.f + __expf(-q0));
        float g1 = 1.f / (1.f + __expf(-q1));
#pragma unroll
        for (int j = 0; j < 8; ++j) {
            m[j] = fmaxf(m[j], a0[j] * g0);
            m[j] = fmaxf(m[j], a1[j] * g1);
        }
    }
    for (; k < k1; ++k) {
        int s = csr_src[k];
        float a0[8];
        cvt8(*(const uint4*)(hub + (((uint32_t)s << 9) + rowOff)), a0);
        float q0 = 0.f;
#pragma unroll
        for (int j = 0; j < 8; ++j) q0 = fmaf(a0[j], b[j], q0);
        q0 += __shfl_xor(q0, 1);
        q0 += __shfl_xor(q0, 2);
        float g0 = 1.f / (1.f + __expf(-q0));
#pragma unroll
        for (int j = 0; j < 8; ++j) m[j] = fmaxf(m[j], a0[j] * g0);
    }

#pragma unroll
    for (int j = 0; j < 8; ++j) m[j] = fmaxf(m[j], __shfl_xor(m[j], 32));

    if (half == 0) {
        bool has = (k1 > k0);
        float hv[8];
        cvt8(*(const uint4*)((const char*)h16 + ((uint32_t)n << 9) + rowOff), hv);
        int rloc = wid * 8 + (l32 >> 2);     // row within block (node-local tau)
        int cbase = (l32 & 3) * 8;
#pragma unroll
        for (int j = 0; j < 8; ++j) {
            float a = has ? m[j] : 0.f;
            float vv = hv[j] + a;
            sc1[rloc][cbase + j] = (vv >= 0.f) ? vv : 0.01f * vv;
        }
    }
    __syncthreads();

    // ---- phase B: h2/hu2 for the block's 64 rows ----
    int w = __builtin_amdgcn_readfirstlane(wid);   // 0..7, SGPR
    int r = l64;                                   // row 0..63
    float h2[4], a2[4];
#pragma unroll
    for (int j = 0; j < 4; ++j) { h2[j] = 0.f; a2[j] = 0.f; }

    const float* Wc = W2  + w * 4;       // uniform -> s_load
    const float* Uc = WU2 + w * 4;       // uniform -> s_load
#pragma unroll 4
    for (int kk = 0; kk < CDIM; ++kk) {
        float xk = sc1[r][kk];           // ds_read_b32, 2-way bank alias
#pragma unroll
        for (int j = 0; j < 4; ++j) {
            h2[j] = fmaf(xk, Wc[kk * CDIM + j], h2[j]);
            a2[j] = fmaf(xk, Uc[kk * CDIM + j], a2[j]);
        }
    }

    size_t rowg = (size_t)blockIdx.x * 64 + r;
    *(uint2*)((char*)h2_16  + rowg * 64 + w * 8) = make_uint2(pk2(h2[0], h2[1]), pk2(h2[2], h2[3]));
    *(uint2*)((char*)hu2_16 + rowg * 64 + w * 8) = make_uint2(pk2(a2[0], a2[1]), pk2(a2[2], a2[3]));
}

// ---------------------------------------------------------------------------
// Final aggregation (layer 2): R13 geometry, writes f32 d_out.
// ---------------------------------------------------------------------------
__global__ __launch_bounds__(256) void agg_kernel(
    const int* __restrict__ offsets,
    const int* __restrict__ csr_src,
    const __half* __restrict__ hu16,
    const __half* __restrict__ h16,
    float* __restrict__ outp)
{
    int tid = threadIdx.x;
    int n = blockIdx.x * 4 + (tid >> 6);
    int l64 = tid & 63;
    int half = l64 >> 5;
    int l32 = l64 & 31;
    uint32_t rowOff = (uint32_t)l32 * 16u;
    const char* hub = (const char*)hu16;

    float b[8];
    cvt8(*(const uint4*)(hub + ((uint32_t)n << 9) + rowOff), b);

    int k0 = offsets[n];
    int k1 = offsets[n + 1];

    float m[8];
#pragma unroll
    for (int j = 0; j < 8; ++j) m[j] = -INFINITY;

    int k = k0;
    int e0 = 0, e1 = 0;
    if (k + 4 <= k1) {
        e0 = csr_src[k + half];
        e1 = csr_src[k + 2 + half];
    }
    while (k + 4 <= k1) {
        uint4 r0 = *(const uint4*)(hub + (((uint32_t)e0 << 9) + rowOff));
        uint4 r1 = *(const uint4*)(hub + (((uint32_t)e1 << 9) + rowOff));
        k += 4;
        if (k + 4 <= k1) {
            e0 = csr_src[k + half];
            e1 = csr_src[k + 2 + half];
        }
        float a0[8], a1[8];
        cvt8(r0, a0); cvt8(r1, a1);
        float q0 = 0.f, q1 = 0.f;
#pragma unroll
        for (int j = 0; j < 8; ++j) { q0 = fmaf(a0[j], b[j], q0); q1 = fmaf(a1[j], b[j], q1); }
        q0 += __shfl_xor(q0, 1); q1 += __shfl_xor(q1, 1);
        q0 += __shfl_xor(q0, 2); q1 += __shfl_xor(q1, 2);
        float g0 = 1.f / (1.f + __expf(-q0));
        float g1 = 1.f / (1.f + __expf(-q1));
#pragma unroll
        for (int j = 0; j < 8; ++j) {
            m[j] = fmaxf(m[j], a0[j] * g0);
            m[j] = fmaxf(m[j], a1[j] * g1);
        }
    }
    for (; k < k1; ++k) {
        int s = csr_src[k];
        float a0[8];
        cvt8(*(const uint4*)(hub + (((uint32_t)s << 9) + rowOff)), a0);
        float q0 = 0.f;
#pragma unroll
        for (int j = 0; j < 8; ++j) q0 = fmaf(a0[j], b[j], q0);
        q0 += __shfl_xor(q0, 1);
        q0 += __shfl_xor(q0, 2);
        float g0 = 1.f / (1.f + __expf(-q0));
#pragma unroll
        for (int j = 0; j < 8; ++j) m[j] = fmaxf(m[j], a0[j] * g0);
    }

#pragma unroll
    for (int j = 0; j < 8; ++j) m[j] = fmaxf(m[j], __shfl_xor(m[j], 32));

    if (half == 0) {
        bool has = (k1 > k0);
        float hv[8];
        cvt8(*(const uint4*)((const char*)h16 + ((uint32_t)n << 9) + rowOff), hv);
        float o[8];
#pragma unroll
        for (int j = 0; j < 8; ++j) {
            float a = has ? m[j] : 0.f;
            float vv = hv[j] + a;
            o[j] = (vv >= 0.f) ? vv : 0.01f * vv;
        }
        uint32_t nodeOff = (uint32_t)n * 1024u + (uint32_t)l32 * 32u;
        char* ob = (char*)outp;
        *(float4*)(ob + nodeOff)      = make_float4(o[0], o[1], o[2], o[3]);
        *(float4*)(ob + nodeOff + 16) = make_float4(o[4], o[5], o[6], o[7]);
    }
}

// ---------------------------------------------------------------------------
// Orchestration: 7 dispatches (R13 structure, proven 138.7us).
// ws: [counts N][offsets N+1][cursor N][WU1 1024][WU2 1024][csr E][pad]
//     [Hh1][HU1][Hh2][HU2] (fp16, 10.24MB each)
// L1: linear2(X)->Hh1,HU1
// fused: agg1(HU1,Hh1) -> c1 in LDS -> h2,hu2 -> Hh2,HU2
// L2: agg(HU2,Hh2) -> d_out (f32)
// ---------------------------------------------------------------------------
extern "C" void kernel_launch(void* const* d_in, const int* in_sizes, int n_in,
                              void* d_out, int out_size, void* d_ws, size_t ws_size,
                              hipStream_t stream)
{
    const float* X   = (const float*)d_in[0];
    const int*   ei  = (const int*)  d_in[1];
    // d_in[2]=edge_attr, d_in[4]=We1, d_in[7]=We2: dead code in reference
    const float* Wn1 = (const float*)d_in[3];
    const float* u1  = (const float*)d_in[5];
    const float* Wn2 = (const float*)d_in[6];
    const float* u2  = (const float*)d_in[8];

    int* counts  = (int*)d_ws;
    int* offsets = counts + NNODES;           // NNODES+1
    int* cursor  = offsets + NNODES + 1;
    float* WU1   = (float*)(cursor + NNODES); // 1024
    float* WU2   = WU1 + 1024;                // 1024
    int* csr     = (int*)(WU2 + 1024);        // NEDGES
    __half* Hh1  = (__half*)(((uintptr_t)(csr + NEDGES) + 255) & ~(uintptr_t)255);
    __half* HU1  = Hh1 + NELEM;
    __half* Hh2  = HU1 + NELEM;
    __half* HU2  = Hh2 + NELEM;

    const int linBlocks  = RROWS / 64;             // 2500
    const int edgeBlocks = (NEDGES + 255) / 256;   // 1250
    const int fuseBlocks = NNODES / 8;             // 2500
    const int aggBlocks  = NNODES / 4;             // 5000

    // ---- CSR + WU build ----
    init_kernel<<<NODEB + 8, 256, 0, stream>>>(Wn1, u1, WU1, Wn2, u2, WU2, counts);
    hist_kernel<<<edgeBlocks, 256, 0, stream>>>(ei, counts);
    scan_kernel<<<NODEB, 256, 0, stream>>>(counts, offsets, cursor);
    scatter_kernel<<<edgeBlocks, 256, 0, stream>>>(ei, cursor, csr);

    // ---- layer 1 linear ----
    linear2_kernel<<<linBlocks, 256, 0, stream>>>(X, Wn1, WU1, Hh1, HU1);

    // ---- fused agg1 + linear2-L2 ----
    aggfuse_kernel<<<fuseBlocks, 512, 0, stream>>>(offsets, csr, HU1, Hh1,
                                                   Wn2, WU2, Hh2, HU2);

    // ---- layer 2 agg -> output ----
    agg_kernel<<<aggBlocks, 256, 0, stream>>>(offsets, csr, HU2, Hh2, (float*)d_out);
}